// Round 4
// baseline (1819.898 us; speedup 1.0000x reference)
//
#include <hip/hip_runtime.h>
#include <math.h>

// ---------------------------------------------------------------------------
// FeatureFusionModule, fully algebraically fused, dtype-adaptive (f32/bf16).
// R3 finding: inputs AND output are float32 (absmax == stub value => d_out
// was half-written with wrong dtype). R4: output path is flag-adaptive; in
// f32 mode fused lives in d_out as f32. Gram uses split-bf16 (hi/lo) MFMA
// in f32 mode for ~2^-17 accuracy.
//  K0  : detect input dtype (f32 vs bf16) -> flag in ws
//  KW  : convert all 19 weight arrays to f32 pool in ws
//  K1  : per-image Gram G = X·Yᵀ (MFMA, split-bf16 in f32 mode) + row sums
//  K2a : 64×64 attention math (logits→softmax→M=A·Wv, T=A·bv) per image
//  K2b : fold attention + conv3x3 + BN into per-image Weff (+indicator ch)
//  K3  : conv via Weff (fp32 VALU) + ReLU + channel sum/max partials -> d_out
//  K4  : CBAM channel MLP -> ch scale
//  K5  : per-pixel channel mean/max of fused*ch -> sp_in
//  K6  : 7x7 spatial conv + sigmoid + final scale (in-place on d_out)
// ---------------------------------------------------------------------------

typedef __bf16 bf16_t;
typedef bf16_t bf16x8 __attribute__((ext_vector_type(8)));
typedef float  f32x4  __attribute__((ext_vector_type(4)));

static constexpr int  CH  = 64;
static constexpr int  H   = 128;
static constexpr int  W   = 128;
static constexpr int  HW  = H * W;          // 16384
static constexpr int  NI  = 16;             // B*S
static constexpr int  NCK = 4;              // gram chunks per image
static constexpr int  ECH = 136;            // 64 X + 64 Y + 1 indicator + 7 pad
static constexpr size_t WEFF_N = (size_t)ECH * 9 * 64;   // floats per image

// ---- f32 weight pool element offsets ----
static constexpr int W_WQ=0, W_BQ=4096, W_WK=4160, W_BK=8256, W_WV=8320, W_BV=12416,
  W_GAMMA=12480, W_WF=12481, W_BF=86209, W_BNG=86273, W_BNB=86337, W_BNM=86401,
  W_BNV=86465, W_FC1W=86529, W_FC1B=87041, W_FC2W=87049, W_FC2B=87561,
  W_SAW=87625, W_SAB=87723, W_TOTAL=87724;

// ---- workspace layout (bytes), total ~9.6 MB ----
static constexpr size_t OFF_GPART  = 0;
static constexpr size_t SZ_GPART   = (size_t)NI*NCK*4096*4;
static constexpr size_t OFF_SX     = OFF_GPART + SZ_GPART;
static constexpr size_t SZ_SXY     = (size_t)NI*NCK*64*4;
static constexpr size_t OFF_SY     = OFF_SX + SZ_SXY;
static constexpr size_t OFF_M1     = OFF_SY + SZ_SXY;
static constexpr size_t SZ_M       = (size_t)NI*4096*4;
static constexpr size_t OFF_M2     = OFF_M1 + SZ_M;
static constexpr size_t OFF_T1     = OFF_M2 + SZ_M;
static constexpr size_t SZ_T       = (size_t)NI*64*4;
static constexpr size_t OFF_T2     = OFF_T1 + SZ_T;
static constexpr size_t OFF_BCONST = OFF_T2 + SZ_T;
static constexpr size_t OFF_WEFF   = OFF_BCONST + 256;
static constexpr size_t SZ_WEFF    = (size_t)NI*WEFF_N*4;
static constexpr size_t OFF_BSUM   = OFF_WEFF + SZ_WEFF;
static constexpr size_t SZ_BST    = (size_t)NI*64*64*4;
static constexpr size_t OFF_BMAX   = OFF_BSUM + SZ_BST;
static constexpr size_t OFF_CHS    = OFF_BMAX + SZ_BST;
static constexpr size_t OFF_SPIN   = OFF_CHS + SZ_T;
static constexpr size_t SZ_SPIN    = (size_t)NI*2*HW*4;
static constexpr size_t OFF_FLAG   = OFF_SPIN + SZ_SPIN;
static constexpr size_t OFF_WF32   = OFF_FLAG + 256;

// ===========================================================================
// K0: dtype detection. bf16 N(0,1) data: exponent field <= ~130 always.
// f32 data read as uint16 pairs: even halves are mantissa bits -> uniform ->
// exponent >= 0xC0 with P~0.25/sample. 4096 samples decide deterministically.
// ===========================================================================
__global__ __launch_bounds__(256) void k0_detect(
    const unsigned short* __restrict__ u, int* __restrict__ flag)
{
  __shared__ int bad;
  if (threadIdx.x == 0) bad = 0;
  __syncthreads();
  int local = 0;
  for (int i = threadIdx.x; i < 4096; i += 256) {
    const unsigned short v = u[2*i];
    const int e = (v >> 7) & 0xFF;
    if (e >= 0xC0) local = 1;
  }
  if (local) atomicOr(&bad, 1);
  __syncthreads();
  if (threadIdx.x == 0) flag[0] = bad;   // 1 => float32 inputs/outputs
}

// ===========================================================================
// KW: convert all weight arrays to f32 pool.  grid (288, 19), block 256
// ===========================================================================
struct WPack { const void* p[19]; int sz[19]; int off[19]; };

__global__ __launch_bounds__(256) void kw_convert(
    WPack wp, const int* __restrict__ flag, float* __restrict__ dst)
{
  const int j = blockIdx.y;
  const int i = blockIdx.x * 256 + threadIdx.x;
  if (i >= wp.sz[j]) return;
  const int f32m = flag[0];
  float v;
  if (f32m) v = ((const float*)wp.p[j])[i];
  else      v = (float)((const bf16_t*)wp.p[j])[i];
  dst[wp.off[j] + i] = v;
}

// ===========================================================================
// K1: partial Gram per (n, chunk).  grid (NCK, 16 n), block 256 (4 waves)
// f32 mode: split-bf16 (hi+lo), G = hh + h*lo + lo*h (3 MFMAs, err ~2^-17)
// A-frag: A[m=lane&15][k=quad*8+j]; D: row=quad*4+reg, col=lane&15 (m89/m91)
// ===========================================================================
__global__ __launch_bounds__(256) void k1_gram(
    const bf16_t* __restrict__ Xb, const bf16_t* __restrict__ Yb,
    const float* __restrict__ Xf, const float* __restrict__ Yf,
    const int* __restrict__ flag,
    float* __restrict__ Gpart, float* __restrict__ sxpart, float* __restrict__ sypart)
{
  const int chunk = blockIdx.x, n = blockIdx.y;
  const int t = threadIdx.x, lane = t & 63, wv = t >> 6;
  const int mrow = lane & 15, quad = lane >> 4;
  const int f32m = flag[0];
  const size_t nbase = (size_t)n * CH * HW;
  const int p0 = chunk * 4096 + wv * 1024;

  f32x4 acc[4][4], acc2[4][4];
  #pragma unroll
  for (int i = 0; i < 4; ++i)
    #pragma unroll
    for (int j = 0; j < 4; ++j) {
      acc[i][j]  = (f32x4){0.f, 0.f, 0.f, 0.f};
      acc2[i][j] = (f32x4){0.f, 0.f, 0.f, 0.f};
    }
  float sxl[4] = {0.f,0.f,0.f,0.f}, syl[4] = {0.f,0.f,0.f,0.f};

  for (int kt = 0; kt < 32; ++kt) {
    const int pk = p0 + kt * 32 + quad * 8;
    if (f32m) {
      bf16x8 a[4], b[4], al[4], bl[4];
      #pragma unroll
      for (int mt = 0; mt < 4; ++mt) {
        const size_t ia = nbase + (size_t)(mt*16 + mrow) * HW + pk;
        float sa = 0.f, sb = 0.f;
        #pragma unroll
        for (int j = 0; j < 8; ++j) {
          const float va = Xf[ia + j];
          const bf16_t ha = (bf16_t)va;
          a[mt][j] = ha; al[mt][j] = (bf16_t)(va - (float)ha); sa += va;
          const float vb = Yf[ia + j];
          const bf16_t hb = (bf16_t)vb;
          b[mt][j] = hb; bl[mt][j] = (bf16_t)(vb - (float)hb); sb += vb;
        }
        sxl[mt] += sa; syl[mt] += sb;
      }
      #pragma unroll
      for (int mt = 0; mt < 4; ++mt)
        #pragma unroll
        for (int nt = 0; nt < 4; ++nt) {
          acc[mt][nt]  = __builtin_amdgcn_mfma_f32_16x16x32_bf16(a[mt],  b[nt],  acc[mt][nt],  0, 0, 0);
          acc2[mt][nt] = __builtin_amdgcn_mfma_f32_16x16x32_bf16(a[mt],  bl[nt], acc2[mt][nt], 0, 0, 0);
          acc2[mt][nt] = __builtin_amdgcn_mfma_f32_16x16x32_bf16(al[mt], b[nt],  acc2[mt][nt], 0, 0, 0);
        }
    } else {
      bf16x8 a[4], b[4];
      #pragma unroll
      for (int mt = 0; mt < 4; ++mt) {
        const size_t ia = nbase + (size_t)(mt*16 + mrow) * HW + pk;
        a[mt] = *(const bf16x8*)(Xb + ia);
        b[mt] = *(const bf16x8*)(Yb + ia);
        float sa = 0.f, sb = 0.f;
        #pragma unroll
        for (int j = 0; j < 8; ++j) { sa += (float)a[mt][j]; sb += (float)b[mt][j]; }
        sxl[mt] += sa; syl[mt] += sb;
      }
      #pragma unroll
      for (int mt = 0; mt < 4; ++mt)
        #pragma unroll
        for (int nt = 0; nt < 4; ++nt)
          acc[mt][nt] = __builtin_amdgcn_mfma_f32_16x16x32_bf16(a[mt], b[nt], acc[mt][nt], 0, 0, 0);
    }
  }

  #pragma unroll
  for (int mt = 0; mt < 4; ++mt) {
    sxl[mt] += __shfl_xor(sxl[mt], 16, 64); sxl[mt] += __shfl_xor(sxl[mt], 32, 64);
    syl[mt] += __shfl_xor(syl[mt], 16, 64); syl[mt] += __shfl_xor(syl[mt], 32, 64);
  }

  __shared__ float Gs[4096];
  __shared__ float sxs[64], sys[64];
  for (int w2 = 0; w2 < 4; ++w2) {
    if (wv == w2) {
      #pragma unroll
      for (int mt = 0; mt < 4; ++mt) {
        #pragma unroll
        for (int nt = 0; nt < 4; ++nt) {
          #pragma unroll
          for (int r = 0; r < 4; ++r) {
            const int c = mt*16 + quad*4 + r, d = nt*16 + mrow;
            const float val = acc[mt][nt][r] + acc2[mt][nt][r];
            if (w2 == 0) Gs[c*64 + d]  = val;
            else         Gs[c*64 + d] += val;
          }
        }
        if (quad == 0) {
          const int c = mt*16 + mrow;
          if (w2 == 0) { sxs[c] = sxl[mt];  sys[c] = syl[mt]; }
          else         { sxs[c] += sxl[mt]; sys[c] += syl[mt]; }
        }
      }
    }
    __syncthreads();
  }
  float* Gp = Gpart + ((size_t)n*NCK + chunk) * 4096;
  for (int i = t; i < 4096; i += 256) Gp[i] = Gs[i];
  if (t < 64)       sxpart[((size_t)n*NCK + chunk)*64 + t]        = sxs[t];
  else if (t < 128) sypart[((size_t)n*NCK + chunk)*64 + (t - 64)] = sys[t - 64];
}

// ===========================================================================
// K2a: attention small math, one block per image (256 threads)
// ===========================================================================
__global__ __launch_bounds__(256) void k2a_attn(
    const float* __restrict__ Gpart, const float* __restrict__ sxpart, const float* __restrict__ sypart,
    const float* __restrict__ wt,
    float* __restrict__ M1, float* __restrict__ M2,
    float* __restrict__ T1, float* __restrict__ T2)
{
  const int n = blockIdx.x, t = threadIdx.x;
  __shared__ float Gs[4096], Gts[4160];          // Gts padded stride 65
  __shared__ float P1s[4096], P2s[4096];
  __shared__ float A1s[4160], A2s[4160];         // padded stride 65
  __shared__ float sxs[64], sys[64], ux[64], uy[64], vx[64], vy[64];

  for (int i = t; i < 4096; i += 256) {
    float s = 0.f;
    for (int c2 = 0; c2 < NCK; ++c2) s += Gpart[((size_t)n*NCK + c2)*4096 + i];
    Gs[i] = s;
    Gts[(i & 63)*65 + (i >> 6)] = s;
  }
  if (t < 64) {
    float s = 0.f; for (int c2 = 0; c2 < NCK; ++c2) s += sxpart[((size_t)n*NCK + c2)*64 + t];
    sxs[t] = s;
  } else if (t < 128) {
    const int c = t - 64;
    float s = 0.f; for (int c2 = 0; c2 < NCK; ++c2) s += sypart[((size_t)n*NCK + c2)*64 + c];
    sys[c] = s;
  }
  __syncthreads();

  // P1 = Wq·G ; P2 = Wq·Gᵀ
  for (int i = t; i < 4096; i += 256) {
    const int c = i >> 6, e = i & 63;
    float s1 = 0.f, s2 = 0.f;
    for (int a = 0; a < 64; ++a) {
      const float w = wt[W_WQ + c*64 + a];
      s1 += w * Gs[a*64 + e];
      s2 += w * Gts[a*65 + e];
    }
    P1s[i] = s1; P2s[i] = s2;
  }
  {
    const int which = t >> 6, c = t & 63;
    float s = 0.f;
    if (which == 0)      { for (int a = 0; a < 64; ++a) s += wt[W_WQ + c*64+a]*sxs[a]; ux[c] = s; }
    else if (which == 1) { for (int a = 0; a < 64; ++a) s += wt[W_WQ + c*64+a]*sys[a]; uy[c] = s; }
    else if (which == 2) { for (int a = 0; a < 64; ++a) s += wt[W_WK + c*64+a]*sxs[a]; vx[c] = s; }
    else                 { for (int a = 0; a < 64; ++a) s += wt[W_WK + c*64+a]*sys[a]; vy[c] = s; }
  }
  __syncthreads();

  // logits: L1 = Wq·G·Wkᵀ + ux·bkᵀ + bq·vyᵀ + HW·bq·bkᵀ ; L2 uses Gᵀ, uy, vx
  for (int i = t; i < 4096; i += 256) {
    const int c = i >> 6, d = i & 63;
    float s1 = 0.f, s2 = 0.f;
    for (int e = 0; e < 64; ++e) {
      const float wk = wt[W_WK + d*64 + e];
      s1 += P1s[c*64 + e] * wk;
      s2 += P2s[c*64 + e] * wk;
    }
    const float bqc = wt[W_BQ + c], bkd = wt[W_BK + d];
    s1 += ux[c]*bkd + bqc*vy[d] + 16384.f*bqc*bkd;
    s2 += uy[c]*bkd + bqc*vx[d] + 16384.f*bqc*bkd;
    A1s[c*65 + d] = s1; A2s[c*65 + d] = s2;
  }
  __syncthreads();

  if (t < 128) {
    float* R = (t < 64) ? (A1s + (t)*65) : (A2s + (t - 64)*65);
    float m = R[0];
    for (int d = 1; d < 64; ++d) m = fmaxf(m, R[d]);
    float s = 0.f;
    for (int d = 0; d < 64; ++d) { const float e2 = expf(R[d] - m); R[d] = e2; s += e2; }
    const float inv = 1.f / s;
    for (int d = 0; d < 64; ++d) R[d] *= inv;
  }
  __syncthreads();

  // M = A·Wv ; T = A·bv
  for (int i = t; i < 4096; i += 256) {
    const int c = i >> 6, e = i & 63;
    float s1 = 0.f, s2 = 0.f;
    for (int d = 0; d < 64; ++d) {
      const float wv = wt[W_WV + d*64 + e];
      s1 += A1s[c*65 + d] * wv;
      s2 += A2s[c*65 + d] * wv;
    }
    M1[(size_t)n*4096 + i] = s1;
    M2[(size_t)n*4096 + i] = s2;
  }
  if (t < 64) {
    float s1 = 0.f, s2 = 0.f;
    for (int d = 0; d < 64; ++d) {
      const float b = wt[W_BV + d];
      s1 += A1s[t*65 + d] * b;
      s2 += A2s[t*65 + d] * b;
    }
    T1[n*64 + t] = s1; T2[n*64 + t] = s2;
  }
}

// ===========================================================================
// K2b: effective conv weights. grid (9 taps, 2 dirs, 16 n), block 256
// ===========================================================================
__global__ __launch_bounds__(256) void k2b_weff(
    const float* __restrict__ wt,
    const float* __restrict__ M1, const float* __restrict__ M2,
    const float* __restrict__ T1, const float* __restrict__ T2,
    float* __restrict__ Weff, float* __restrict__ bconst)
{
  const int tap = blockIdx.x, dir = blockIdx.y, n = blockIdx.z;
  const int t = threadIdx.x;
  const float g = wt[W_GAMMA];
  float* Wn = Weff + (size_t)n * WEFF_N;
  const float* Mo = (dir == 0) ? (M2 + (size_t)n*4096) : (M1 + (size_t)n*4096);

  for (int i = t; i < 4096; i += 256) {
    const int o = i & 63, e = i >> 6;
    const float inv = wt[W_BNG + o] * rsqrtf(wt[W_BNV + o] + 1e-5f);
    const float base = (dir == 0) ? wt[W_WF + (o*128 + e)*9 + tap]
                                  : wt[W_WF + (o*128 + 64 + e)*9 + tap];
    float s = 0.f;
    for (int c = 0; c < 64; ++c) {
      const float wf = (dir == 0) ? wt[W_WF + (o*128 + 64 + c)*9 + tap]
                                  : wt[W_WF + (o*128 + c)*9 + tap];
      s += wf * Mo[c*64 + e];
    }
    const int ee = dir*64 + e;
    Wn[((size_t)ee*9 + tap)*64 + o] = inv * (base + g * s);
  }

  if (dir == 0) {
    for (int i = t; i < 8*64; i += 256) {
      const int ee = 128 + (i >> 6), o = i & 63;
      float w = 0.f;
      if (ee == 128) {
        const float inv = wt[W_BNG + o] * rsqrtf(wt[W_BNV + o] + 1e-5f);
        float s = 0.f;
        for (int c = 0; c < 64; ++c)
          s += wt[W_WF + (o*128 + c)*9 + tap]      * T1[n*64 + c]
             + wt[W_WF + (o*128 + 64 + c)*9 + tap] * T2[n*64 + c];
        w = inv * g * s;
      }
      Wn[((size_t)ee*9 + tap)*64 + o] = w;
    }
    if (tap == 0 && n == 0 && t < 64) {
      const int o = t;
      const float inv = wt[W_BNG + o] * rsqrtf(wt[W_BNV + o] + 1e-5f);
      bconst[o] = wt[W_BF + o]*inv + wt[W_BNB + o] - wt[W_BNM + o]*inv;
    }
  }
}

// ===========================================================================
// K3: folded conv3x3 + BN + ReLU + channel-stat partials. Output dtype per flag.
// grid (64 row-pairs, 16 n), block 256 (one pixel per thread, 2 rows x 128)
// ===========================================================================
__global__ __launch_bounds__(256) void k3_conv(
    const bf16_t* __restrict__ Xb, const bf16_t* __restrict__ Yb,
    const float* __restrict__ Xf, const float* __restrict__ Yf,
    const int* __restrict__ flag,
    const float* __restrict__ Weff, const float* __restrict__ bconst,
    bf16_t* __restrict__ fusedB, float* __restrict__ fusedF,
    float* __restrict__ bsum, float* __restrict__ bmax)
{
  __shared__ float sbuf[2][8][4][130];
  __shared__ float ssum[4][64], smax[4][64];
  const int rp = blockIdx.x, n = blockIdx.y;
  const int t = threadIdx.x;
  const int y0 = rp * 2;
  const int f32m = flag[0];
  const size_t nbase = (size_t)n * CH * HW;
  const float* __restrict__ wn = Weff + (size_t)n * WEFF_N;

  float acc[64];
  #pragma unroll
  for (int o = 0; o < 64; ++o) acc[o] = 0.f;

  auto stage = [&](int gs, int bsel) {
    const int gbase = gs * 8;
    #pragma unroll
    for (int i = 0; i < 16; ++i) {
      const int idx = t + 256*i;
      const int ch = idx >> 9, rem = idx & 511;
      const int r = rem >> 7, col = rem & 127;
      const int ee = gbase + ch;
      const int gy = y0 - 1 + r;
      float val = 0.f;
      if (gy >= 0 && gy < H) {
        if (ee < 64) {
          const size_t q = nbase + (size_t)ee*HW + gy*W + col;
          val = f32m ? Xf[q] : (float)Xb[q];
        } else if (ee < 128) {
          const size_t q = nbase + (size_t)(ee - 64)*HW + gy*W + col;
          val = f32m ? Yf[q] : (float)Yb[q];
        } else if (ee == 128) val = 1.f;
      }
      sbuf[bsel][ch][r][col + 1] = val;
    }
    if (t < 64) {
      const int ch = t >> 3, r = (t >> 1) & 3, side = t & 1;
      sbuf[bsel][ch][r][side * 129] = 0.f;
    }
  };

  stage(0, 0);
  __syncthreads();

  const int ly = t >> 7, x = t & 127;

  #pragma clang loop unroll(disable)
  for (int g = 0; g < 17; ++g) {
    const int cur = g & 1;
    if (g < 16) stage(g + 1, cur ^ 1);
    #pragma unroll
    for (int esub = 0; esub < 8; ++esub) {
      float xv[9];
      #pragma unroll
      for (int ky = 0; ky < 3; ++ky) {
        #pragma unroll
        for (int kx = 0; kx < 3; ++kx)
          xv[ky*3 + kx] = sbuf[cur][esub][ly + ky][x + kx];
      }
      const float* __restrict__ wr = wn + (size_t)(g*8 + esub) * 9 * 64;
      #pragma unroll
      for (int tap = 0; tap < 9; ++tap) {
        const float xt = xv[tap];
        const float* __restrict__ wrow = wr + tap * 64;
        #pragma unroll
        for (int o = 0; o < 64; ++o) acc[o] = fmaf(wrow[o], xt, acc[o]);
      }
    }
    __syncthreads();
  }

  const int lane = t & 63, wv = t >> 6;
  const int gy = y0 + ly, p = gy * W + x;
  #pragma unroll
  for (int o = 0; o < 64; ++o) {
    const float v = fmaxf(acc[o] + bconst[o], 0.f);
    if (f32m) fusedF[nbase + (size_t)o * HW + p] = v;
    else      fusedB[nbase + (size_t)o * HW + p] = (bf16_t)v;
    float s = v, m = v;
    #pragma unroll
    for (int d2 = 32; d2; d2 >>= 1) {
      s += __shfl_xor(s, d2, 64);
      m = fmaxf(m, __shfl_xor(m, d2, 64));
    }
    if (lane == 0) { ssum[wv][o] = s; smax[wv][o] = m; }
  }
  __syncthreads();
  if (t < 64) {
    const float S = ssum[0][t] + ssum[1][t] + ssum[2][t] + ssum[3][t];
    const float M = fmaxf(fmaxf(smax[0][t], smax[1][t]), fmaxf(smax[2][t], smax[3][t]));
    bsum[((size_t)n*64 + rp)*64 + t] = S;
    bmax[((size_t)n*64 + rp)*64 + t] = M;
  }
}

// ===========================================================================
// K4: CBAM channel gate.  grid 16 (per n), block 64
// ===========================================================================
__global__ __launch_bounds__(64) void k4_chgate(
    const float* __restrict__ bsum, const float* __restrict__ bmax,
    const float* __restrict__ wt, float* __restrict__ chout)
{
  const int n = blockIdx.x, t = threadIdx.x;
  __shared__ float avg[64], mxs[64], h1[8], h2[8];
  float S = 0.f, M = 0.f;
  for (int rp = 0; rp < 64; ++rp) {
    S += bsum[((size_t)n*64 + rp)*64 + t];
    M = fmaxf(M, bmax[((size_t)n*64 + rp)*64 + t]);
  }
  avg[t] = S * (1.f / 16384.f);
  mxs[t] = M;
  __syncthreads();
  if (t < 8) {
    float s = wt[W_FC1B + t];
    for (int c = 0; c < 64; ++c) s += wt[W_FC1W + t*64 + c] * avg[c];
    h1[t] = fmaxf(s, 0.f);
  } else if (t < 16) {
    const int r = t - 8;
    float s = wt[W_FC1B + r];
    for (int c = 0; c < 64; ++c) s += wt[W_FC1W + r*64 + c] * mxs[c];
    h2[r] = fmaxf(s, 0.f);
  }
  __syncthreads();
  float s = 2.f * wt[W_FC2B + t];
  for (int r = 0; r < 8; ++r) s += wt[W_FC2W + t*8 + r] * (h1[r] + h2[r]);
  chout[n*64 + t] = 1.f / (1.f + expf(-s));
}

// ===========================================================================
// K5: spatial-attention inputs (per-pixel channel mean/max of fused*ch)
// ===========================================================================
__global__ __launch_bounds__(256) void k5_spin(
    const bf16_t* __restrict__ fusedB, const float* __restrict__ fusedF,
    const int* __restrict__ flag,
    const float* __restrict__ chs, float* __restrict__ spin)
{
  const int n = blockIdx.y;
  const int p = blockIdx.x * 256 + threadIdx.x;
  const int f32m = flag[0];
  const size_t nbase = (size_t)n * CH * HW;
  const float* c = chs + n * 64;
  float s = 0.f, m = 0.f;                       // fused>=0, ch>0 => init 0 ok
  for (int o = 0; o < 64; ++o) {
    const float fv = f32m ? fusedF[nbase + (size_t)o*HW + p]
                          : (float)fusedB[nbase + (size_t)o*HW + p];
    const float v = fv * c[o];
    s += v; m = fmaxf(m, v);
  }
  spin[(size_t)n*2*HW + p]      = s * (1.f / 64.f);
  spin[(size_t)n*2*HW + HW + p] = m;
}

// ===========================================================================
// K6: 7x7 spatial conv + sigmoid + final scale (in-place on d_out, per flag)
// ===========================================================================
__global__ __launch_bounds__(256) void k6_final(
    bf16_t* __restrict__ fusedB, float* __restrict__ fusedF,
    const int* __restrict__ flag,
    const float* __restrict__ chs, const float* __restrict__ spin,
    const float* __restrict__ wt)
{
  const int n = blockIdx.y;
  const int p = blockIdx.x * 256 + threadIdx.x;
  const int y = p >> 7, x = p & 127;
  const int f32m = flag[0];
  const float* s0 = spin + (size_t)n*2*HW;
  const float* s1 = s0 + HW;
  float s = wt[W_SAB];
  for (int j = 0; j < 7; ++j) {
    const int yy = y + j - 3;
    if (yy < 0 || yy >= H) continue;
    for (int i = 0; i < 7; ++i) {
      const int xx = x + i - 3;
      if (xx < 0 || xx >= W) continue;
      const int q = yy * W + xx;
      s += wt[W_SAW + j*7 + i] * s0[q] + wt[W_SAW + 49 + j*7 + i] * s1[q];
    }
  }
  const float sp = 1.f / (1.f + expf(-s));
  const size_t nbase = (size_t)n * CH * HW;
  const float* c = chs + n * 64;
  for (int o = 0; o < 64; ++o) {
    const size_t q = nbase + (size_t)o*HW + p;
    if (f32m) fusedF[q] = fusedF[q] * c[o] * sp;
    else      fusedB[q] = (bf16_t)((float)fusedB[q] * c[o] * sp);
  }
}

// ===========================================================================
extern "C" void kernel_launch(void* const* d_in, const int* in_sizes, int n_in,
                              void* d_out, int out_size, void* d_ws, size_t ws_size,
                              hipStream_t stream)
{
  (void)n_in; (void)out_size; (void)ws_size; (void)in_sizes;
  char* ws = (char*)d_ws;
  float*  Gpart  = (float*)(ws + OFF_GPART);
  float*  sxp    = (float*)(ws + OFF_SX);
  float*  syp    = (float*)(ws + OFF_SY);
  float*  M1     = (float*)(ws + OFF_M1);
  float*  M2     = (float*)(ws + OFF_M2);
  float*  T1     = (float*)(ws + OFF_T1);
  float*  T2     = (float*)(ws + OFF_T2);
  float*  bconst = (float*)(ws + OFF_BCONST);
  float*  Weff   = (float*)(ws + OFF_WEFF);
  float*  bsum   = (float*)(ws + OFF_BSUM);
  float*  bmax   = (float*)(ws + OFF_BMAX);
  float*  chs    = (float*)(ws + OFF_CHS);
  float*  spin   = (float*)(ws + OFF_SPIN);
  int*    flag   = (int*)  (ws + OFF_FLAG);
  float*  wf32   = (float*)(ws + OFF_WF32);
  bf16_t* fusedB = (bf16_t*)d_out;
  float*  fusedF = (float*)d_out;

  const bf16_t* imgB = (const bf16_t*)d_in[0];
  const bf16_t* depB = (const bf16_t*)d_in[1];
  const float*  imgF = (const float*) d_in[0];
  const float*  depF = (const float*) d_in[1];

  WPack wp;
  static const int wsz[19] = {4096,64,4096,64,4096,64,1,73728,64,64,64,64,64,512,8,512,64,98,1};
  static const int woff[19] = {W_WQ,W_BQ,W_WK,W_BK,W_WV,W_BV,W_GAMMA,W_WF,W_BF,W_BNG,
                               W_BNB,W_BNM,W_BNV,W_FC1W,W_FC1B,W_FC2W,W_FC2B,W_SAW,W_SAB};
  for (int j = 0; j < 19; ++j) { wp.p[j] = d_in[2 + j]; wp.sz[j] = wsz[j]; wp.off[j] = woff[j]; }

  hipLaunchKernelGGL(k0_detect, dim3(1), dim3(256), 0, stream,
                     (const unsigned short*)d_in[0], flag);
  hipLaunchKernelGGL(kw_convert, dim3(288, 19), dim3(256), 0, stream, wp, flag, wf32);
  hipLaunchKernelGGL(k1_gram,  dim3(NCK, NI), dim3(256), 0, stream,
                     imgB, depB, imgF, depF, flag, Gpart, sxp, syp);
  hipLaunchKernelGGL(k2a_attn, dim3(NI), dim3(256), 0, stream,
                     Gpart, sxp, syp, wf32, M1, M2, T1, T2);
  hipLaunchKernelGGL(k2b_weff, dim3(9, 2, NI), dim3(256), 0, stream,
                     wf32, M1, M2, T1, T2, Weff, bconst);
  hipLaunchKernelGGL(k3_conv,  dim3(64, NI), dim3(256), 0, stream,
                     imgB, depB, imgF, depF, flag, Weff, bconst, fusedB, fusedF, bsum, bmax);
  hipLaunchKernelGGL(k4_chgate, dim3(NI), dim3(64), 0, stream,
                     bsum, bmax, wf32, chs);
  hipLaunchKernelGGL(k5_spin,  dim3(64, NI), dim3(256), 0, stream,
                     fusedB, fusedF, flag, chs, spin);
  hipLaunchKernelGGL(k6_final, dim3(64, NI), dim3(256), 0, stream,
                     fusedB, fusedF, flag, chs, spin, wf32);
}

// Round 5
// 835.680 us; speedup vs baseline: 2.1777x; 2.1777x over previous
//
#include <hip/hip_runtime.h>
#include <math.h>

// ---------------------------------------------------------------------------
// FeatureFusionModule, algebraically fused, dtype-adaptive (f32/bf16).
// R5: K3 rewritten as fp16 MFMA implicit GEMM (K = 128 ech x 9 taps = 1152),
//     border constants via ind[9][64] epilogue table (K2c), K1 NCK 4->16.
//  K0  : detect input dtype (f32 vs bf16) -> flag in ws
//  KW  : convert all 19 weight arrays to f32 pool in ws
//  K1  : per-image Gram G = X·Yᵀ (MFMA, split-bf16 in f32 mode) + row sums
//  K2a : 64×64 attention math (logits→softmax→M=A·Wv, T=A·bv) per image
//  K2b : fold attention + conv3x3 + BN into fp16 Wh[n][o][tap][128] + windT
//  K2c : border-case indicator sums ind[n][3yc*3xc][64]
//  K3  : implicit-GEMM conv (MFMA f16) + ReLU + channel stats -> d_out
//  K4  : CBAM channel MLP -> ch scale
//  K5  : per-pixel channel mean/max of fused*ch -> sp_in
//  K6  : 7x7 spatial conv + sigmoid + final scale (in-place on d_out)
// ---------------------------------------------------------------------------

typedef __bf16 bf16_t;
typedef bf16_t bf16x8 __attribute__((ext_vector_type(8)));
typedef bf16_t bf16x4 __attribute__((ext_vector_type(4)));
typedef float  f32x4  __attribute__((ext_vector_type(4)));
typedef _Float16 f16_t;
typedef f16_t  f16x8  __attribute__((ext_vector_type(8)));

static constexpr int  CH  = 64;
static constexpr int  H   = 128;
static constexpr int  W   = 128;
static constexpr int  HW  = H * W;          // 16384
static constexpr int  NI  = 16;             // B*S
static constexpr int  NCK = 16;             // gram chunks per image

// ---- f32 weight pool element offsets ----
static constexpr int W_WQ=0, W_BQ=4096, W_WK=4160, W_BK=8256, W_WV=8320, W_BV=12416,
  W_GAMMA=12480, W_WF=12481, W_BF=86209, W_BNG=86273, W_BNB=86337, W_BNM=86401,
  W_BNV=86465, W_FC1W=86529, W_FC1B=87041, W_FC2W=87049, W_FC2B=87561,
  W_SAW=87625, W_SAB=87723, W_TOTAL=87724;

// ---- workspace layout (bytes), total ~9.9 MB ----
static constexpr size_t OFF_GPART  = 0;
static constexpr size_t SZ_GPART   = (size_t)NI*NCK*4096*4;
static constexpr size_t OFF_SX     = OFF_GPART + SZ_GPART;
static constexpr size_t SZ_SXY     = (size_t)NI*NCK*64*4;
static constexpr size_t OFF_SY     = OFF_SX + SZ_SXY;
static constexpr size_t OFF_M1     = OFF_SY + SZ_SXY;
static constexpr size_t SZ_M       = (size_t)NI*4096*4;
static constexpr size_t OFF_M2     = OFF_M1 + SZ_M;
static constexpr size_t OFF_T1     = OFF_M2 + SZ_M;
static constexpr size_t SZ_T       = (size_t)NI*64*4;
static constexpr size_t OFF_T2     = OFF_T1 + SZ_T;
static constexpr size_t OFF_BCONST = OFF_T2 + SZ_T;
static constexpr size_t OFF_WH     = OFF_BCONST + 256;                  // fp16 weights
static constexpr size_t SZ_WH      = (size_t)NI*64*9*128*2;
static constexpr size_t OFF_WINDT  = OFF_WH + SZ_WH;                    // NI*9*64 f32
static constexpr size_t SZ_WIND    = (size_t)NI*9*64*4;
static constexpr size_t OFF_IND    = OFF_WINDT + SZ_WIND;               // NI*9*64 f32
static constexpr size_t OFF_BSUM   = OFF_IND + SZ_WIND;
static constexpr size_t SZ_BST     = (size_t)NI*64*64*4;
static constexpr size_t OFF_BMAX   = OFF_BSUM + SZ_BST;
static constexpr size_t OFF_CHS    = OFF_BMAX + SZ_BST;
static constexpr size_t OFF_SPIN   = OFF_CHS + SZ_T;
static constexpr size_t SZ_SPIN    = (size_t)NI*2*HW*4;
static constexpr size_t OFF_FLAG   = OFF_SPIN + SZ_SPIN;
static constexpr size_t OFF_WF32   = OFF_FLAG + 256;

// ===========================================================================
// K0: dtype detection (bf16 N(0,1) never has exponent >= 0xC0 in even u16s)
// ===========================================================================
__global__ __launch_bounds__(256) void k0_detect(
    const unsigned short* __restrict__ u, int* __restrict__ flag)
{
  __shared__ int bad;
  if (threadIdx.x == 0) bad = 0;
  __syncthreads();
  int local = 0;
  for (int i = threadIdx.x; i < 4096; i += 256) {
    const unsigned short v = u[2*i];
    const int e = (v >> 7) & 0xFF;
    if (e >= 0xC0) local = 1;
  }
  if (local) atomicOr(&bad, 1);
  __syncthreads();
  if (threadIdx.x == 0) flag[0] = bad;   // 1 => float32 inputs/outputs
}

// ===========================================================================
// KW: convert all weight arrays to f32 pool.  grid (288, 19), block 256
// ===========================================================================
struct WPack { const void* p[19]; int sz[19]; int off[19]; };

__global__ __launch_bounds__(256) void kw_convert(
    WPack wp, const int* __restrict__ flag, float* __restrict__ dst)
{
  const int j = blockIdx.y;
  const int i = blockIdx.x * 256 + threadIdx.x;
  if (i >= wp.sz[j]) return;
  const int f32m = flag[0];
  float v;
  if (f32m) v = ((const float*)wp.p[j])[i];
  else      v = (float)((const bf16_t*)wp.p[j])[i];
  dst[wp.off[j] + i] = v;
}

// ===========================================================================
// K1: partial Gram per (n, chunk).  grid (NCK=16, 16 n), block 256 (4 waves)
// f32 mode: split-bf16 (hi+lo), 3 MFMAs; D: row=quad*4+reg, col=lane&15
// ===========================================================================
__global__ __launch_bounds__(256) void k1_gram(
    const bf16_t* __restrict__ Xb, const bf16_t* __restrict__ Yb,
    const float* __restrict__ Xf, const float* __restrict__ Yf,
    const int* __restrict__ flag,
    float* __restrict__ Gpart, float* __restrict__ sxpart, float* __restrict__ sypart)
{
  const int chunk = blockIdx.x, n = blockIdx.y;
  const int t = threadIdx.x, lane = t & 63, wv = t >> 6;
  const int mrow = lane & 15, quad = lane >> 4;
  const int f32m = flag[0];
  const size_t nbase = (size_t)n * CH * HW;
  const int p0 = chunk * 1024 + wv * 256;

  f32x4 acc[4][4], acc2[4][4];
  #pragma unroll
  for (int i = 0; i < 4; ++i)
    #pragma unroll
    for (int j = 0; j < 4; ++j) {
      acc[i][j]  = (f32x4){0.f, 0.f, 0.f, 0.f};
      acc2[i][j] = (f32x4){0.f, 0.f, 0.f, 0.f};
    }
  float sxl[4] = {0.f,0.f,0.f,0.f}, syl[4] = {0.f,0.f,0.f,0.f};

  for (int kt = 0; kt < 8; ++kt) {
    const int pk = p0 + kt * 32 + quad * 8;
    if (f32m) {
      bf16x8 a[4], b[4], al[4], bl[4];
      #pragma unroll
      for (int mt = 0; mt < 4; ++mt) {
        const size_t ia = nbase + (size_t)(mt*16 + mrow) * HW + pk;
        float sa = 0.f, sb = 0.f;
        #pragma unroll
        for (int j = 0; j < 8; ++j) {
          const float va = Xf[ia + j];
          const bf16_t ha = (bf16_t)va;
          a[mt][j] = ha; al[mt][j] = (bf16_t)(va - (float)ha); sa += va;
          const float vb = Yf[ia + j];
          const bf16_t hb = (bf16_t)vb;
          b[mt][j] = hb; bl[mt][j] = (bf16_t)(vb - (float)hb); sb += vb;
        }
        sxl[mt] += sa; syl[mt] += sb;
      }
      #pragma unroll
      for (int mt = 0; mt < 4; ++mt)
        #pragma unroll
        for (int nt = 0; nt < 4; ++nt) {
          acc[mt][nt]  = __builtin_amdgcn_mfma_f32_16x16x32_bf16(a[mt],  b[nt],  acc[mt][nt],  0, 0, 0);
          acc2[mt][nt] = __builtin_amdgcn_mfma_f32_16x16x32_bf16(a[mt],  bl[nt], acc2[mt][nt], 0, 0, 0);
          acc2[mt][nt] = __builtin_amdgcn_mfma_f32_16x16x32_bf16(al[mt], b[nt],  acc2[mt][nt], 0, 0, 0);
        }
    } else {
      bf16x8 a[4], b[4];
      #pragma unroll
      for (int mt = 0; mt < 4; ++mt) {
        const size_t ia = nbase + (size_t)(mt*16 + mrow) * HW + pk;
        a[mt] = *(const bf16x8*)(Xb + ia);
        b[mt] = *(const bf16x8*)(Yb + ia);
        float sa = 0.f, sb = 0.f;
        #pragma unroll
        for (int j = 0; j < 8; ++j) { sa += (float)a[mt][j]; sb += (float)b[mt][j]; }
        sxl[mt] += sa; syl[mt] += sb;
      }
      #pragma unroll
      for (int mt = 0; mt < 4; ++mt)
        #pragma unroll
        for (int nt = 0; nt < 4; ++nt)
          acc[mt][nt] = __builtin_amdgcn_mfma_f32_16x16x32_bf16(a[mt], b[nt], acc[mt][nt], 0, 0, 0);
    }
  }

  #pragma unroll
  for (int mt = 0; mt < 4; ++mt) {
    sxl[mt] += __shfl_xor(sxl[mt], 16, 64); sxl[mt] += __shfl_xor(sxl[mt], 32, 64);
    syl[mt] += __shfl_xor(syl[mt], 16, 64); syl[mt] += __shfl_xor(syl[mt], 32, 64);
  }

  __shared__ float Gs[4096];
  __shared__ float sxs[64], sys[64];
  for (int w2 = 0; w2 < 4; ++w2) {
    if (wv == w2) {
      #pragma unroll
      for (int mt = 0; mt < 4; ++mt) {
        #pragma unroll
        for (int nt = 0; nt < 4; ++nt) {
          #pragma unroll
          for (int r = 0; r < 4; ++r) {
            const int c = mt*16 + quad*4 + r, d = nt*16 + mrow;
            const float val = acc[mt][nt][r] + acc2[mt][nt][r];
            if (w2 == 0) Gs[c*64 + d]  = val;
            else         Gs[c*64 + d] += val;
          }
        }
        if (quad == 0) {
          const int c = mt*16 + mrow;
          if (w2 == 0) { sxs[c] = sxl[mt];  sys[c] = syl[mt]; }
          else         { sxs[c] += sxl[mt]; sys[c] += syl[mt]; }
        }
      }
    }
    __syncthreads();
  }
  float* Gp = Gpart + ((size_t)n*NCK + chunk) * 4096;
  for (int i = t; i < 4096; i += 256) Gp[i] = Gs[i];
  if (t < 64)       sxpart[((size_t)n*NCK + chunk)*64 + t]        = sxs[t];
  else if (t < 128) sypart[((size_t)n*NCK + chunk)*64 + (t - 64)] = sys[t - 64];
}

// ===========================================================================
// K2a: attention small math, one block per image (256 threads)
// ===========================================================================
__global__ __launch_bounds__(256) void k2a_attn(
    const float* __restrict__ Gpart, const float* __restrict__ sxpart, const float* __restrict__ sypart,
    const float* __restrict__ wt,
    float* __restrict__ M1, float* __restrict__ M2,
    float* __restrict__ T1, float* __restrict__ T2)
{
  const int n = blockIdx.x, t = threadIdx.x;
  __shared__ float Gs[4096], Gts[4160];
  __shared__ float P1s[4096], P2s[4096];
  __shared__ float A1s[4160], A2s[4160];
  __shared__ float sxs[64], sys[64], ux[64], uy[64], vx[64], vy[64];

  for (int i = t; i < 4096; i += 256) {
    float s = 0.f;
    for (int c2 = 0; c2 < NCK; ++c2) s += Gpart[((size_t)n*NCK + c2)*4096 + i];
    Gs[i] = s;
    Gts[(i & 63)*65 + (i >> 6)] = s;
  }
  if (t < 64) {
    float s = 0.f; for (int c2 = 0; c2 < NCK; ++c2) s += sxpart[((size_t)n*NCK + c2)*64 + t];
    sxs[t] = s;
  } else if (t < 128) {
    const int c = t - 64;
    float s = 0.f; for (int c2 = 0; c2 < NCK; ++c2) s += sypart[((size_t)n*NCK + c2)*64 + c];
    sys[c] = s;
  }
  __syncthreads();

  for (int i = t; i < 4096; i += 256) {
    const int c = i >> 6, e = i & 63;
    float s1 = 0.f, s2 = 0.f;
    for (int a = 0; a < 64; ++a) {
      const float w = wt[W_WQ + c*64 + a];
      s1 += w * Gs[a*64 + e];
      s2 += w * Gts[a*65 + e];
    }
    P1s[i] = s1; P2s[i] = s2;
  }
  {
    const int which = t >> 6, c = t & 63;
    float s = 0.f;
    if (which == 0)      { for (int a = 0; a < 64; ++a) s += wt[W_WQ + c*64+a]*sxs[a]; ux[c] = s; }
    else if (which == 1) { for (int a = 0; a < 64; ++a) s += wt[W_WQ + c*64+a]*sys[a]; uy[c] = s; }
    else if (which == 2) { for (int a = 0; a < 64; ++a) s += wt[W_WK + c*64+a]*sxs[a]; vx[c] = s; }
    else                 { for (int a = 0; a < 64; ++a) s += wt[W_WK + c*64+a]*sys[a]; vy[c] = s; }
  }
  __syncthreads();

  for (int i = t; i < 4096; i += 256) {
    const int c = i >> 6, d = i & 63;
    float s1 = 0.f, s2 = 0.f;
    for (int e = 0; e < 64; ++e) {
      const float wk = wt[W_WK + d*64 + e];
      s1 += P1s[c*64 + e] * wk;
      s2 += P2s[c*64 + e] * wk;
    }
    const float bqc = wt[W_BQ + c], bkd = wt[W_BK + d];
    s1 += ux[c]*bkd + bqc*vy[d] + 16384.f*bqc*bkd;
    s2 += uy[c]*bkd + bqc*vx[d] + 16384.f*bqc*bkd;
    A1s[c*65 + d] = s1; A2s[c*65 + d] = s2;
  }
  __syncthreads();

  if (t < 128) {
    float* R = (t < 64) ? (A1s + (t)*65) : (A2s + (t - 64)*65);
    float m = R[0];
    for (int d = 1; d < 64; ++d) m = fmaxf(m, R[d]);
    float s = 0.f;
    for (int d = 0; d < 64; ++d) { const float e2 = expf(R[d] - m); R[d] = e2; s += e2; }
    const float inv = 1.f / s;
    for (int d = 0; d < 64; ++d) R[d] *= inv;
  }
  __syncthreads();

  for (int i = t; i < 4096; i += 256) {
    const int c = i >> 6, e = i & 63;
    float s1 = 0.f, s2 = 0.f;
    for (int d = 0; d < 64; ++d) {
      const float wv = wt[W_WV + d*64 + e];
      s1 += A1s[c*65 + d] * wv;
      s2 += A2s[c*65 + d] * wv;
    }
    M1[(size_t)n*4096 + i] = s1;
    M2[(size_t)n*4096 + i] = s2;
  }
  if (t < 64) {
    float s1 = 0.f, s2 = 0.f;
    for (int d = 0; d < 64; ++d) {
      const float b = wt[W_BV + d];
      s1 += A1s[t*65 + d] * b;
      s2 += A2s[t*65 + d] * b;
    }
    T1[n*64 + t] = s1; T2[n*64 + t] = s2;
  }
}

// ===========================================================================
// K2b: effective conv weights -> fp16 Wh[n][o][tap][128] (+windT, bconst).
// grid (9 taps, 2 dirs, 16 n), block 256
// ===========================================================================
__global__ __launch_bounds__(256) void k2b_weff(
    const float* __restrict__ wt,
    const float* __restrict__ M1, const float* __restrict__ M2,
    const float* __restrict__ T1, const float* __restrict__ T2,
    f16_t* __restrict__ Wh, float* __restrict__ windT, float* __restrict__ bconst)
{
  const int tap = blockIdx.x, dir = blockIdx.y, n = blockIdx.z;
  const int t = threadIdx.x;
  const float g = wt[W_GAMMA];
  f16_t* Whn = Wh + (size_t)n * 64 * 9 * 128;
  const float* Mo = (dir == 0) ? (M2 + (size_t)n*4096) : (M1 + (size_t)n*4096);

  for (int i = t; i < 4096; i += 256) {
    const int o = i & 63, e = i >> 6;
    const float inv = wt[W_BNG + o] * rsqrtf(wt[W_BNV + o] + 1e-5f);
    const float base = (dir == 0) ? wt[W_WF + (o*128 + e)*9 + tap]
                                  : wt[W_WF + (o*128 + 64 + e)*9 + tap];
    float s = 0.f;
    for (int c = 0; c < 64; ++c) {
      const float wf = (dir == 0) ? wt[W_WF + (o*128 + 64 + c)*9 + tap]
                                  : wt[W_WF + (o*128 + c)*9 + tap];
      s += wf * Mo[c*64 + e];
    }
    Whn[(o*9 + tap)*128 + dir*64 + e] = (f16_t)(inv * (base + g * s));
  }

  if (dir == 0) {
    if (t < 64) {
      const int o = t;
      const float inv = wt[W_BNG + o] * rsqrtf(wt[W_BNV + o] + 1e-5f);
      float s = 0.f;
      for (int c = 0; c < 64; ++c)
        s += wt[W_WF + (o*128 + c)*9 + tap]      * T1[n*64 + c]
           + wt[W_WF + (o*128 + 64 + c)*9 + tap] * T2[n*64 + c];
      windT[((size_t)n*9 + tap)*64 + o] = inv * g * s;
      if (tap == 0 && n == 0)
        bconst[o] = wt[W_BF + o]*inv + wt[W_BNB + o] - wt[W_BNM + o]*inv;
    }
  }
}

// ===========================================================================
// K2c: border indicator table ind[n][yc*3+xc][64].  grid NI, block 64
// ===========================================================================
__global__ __launch_bounds__(64) void k2c_ind(
    const float* __restrict__ windT, float* __restrict__ ind)
{
  const int n = blockIdx.x, o = threadIdx.x;
  float w9[9];
  #pragma unroll
  for (int tp = 0; tp < 9; ++tp) w9[tp] = windT[((size_t)n*9 + tp)*64 + o];
  #pragma unroll
  for (int yc = 0; yc < 3; ++yc) {
    const int ky0 = (yc == 0) ? 1 : 0, ky1 = (yc == 2) ? 1 : 2;
    #pragma unroll
    for (int xc = 0; xc < 3; ++xc) {
      const int kx0 = (xc == 0) ? 1 : 0, kx1 = (xc == 2) ? 1 : 2;
      float s = 0.f;
      for (int ky = ky0; ky <= ky1; ++ky)
        for (int kx = kx0; kx <= kx1; ++kx) s += w9[ky*3 + kx];
      ind[((size_t)n*9 + yc*3 + xc)*64 + o] = s;
    }
  }
}

// ===========================================================================
// K3: implicit-GEMM conv via MFMA f16.
// grid (64 row-pairs, 16 n), block 256 (4 waves).
// Wave wv: row ly=wv>>1, col-half ch2=wv&1 -> 64 px x 64 out, acc 4x4 tiles.
// LDS sbuf[4 rows][130 cols][40 f16]: slots (oct^(col&3))*8 .. +7 hold ech
// oct*8..+7 of current 32-ech slab (XOR swizzle => <=2-way banks both ways).
// Halo cols 0,129 are always zero (written once). K-order: slab(4) x tap(9).
// ===========================================================================
__global__ __launch_bounds__(256) void k3_conv(
    const bf16_t* __restrict__ Xb, const bf16_t* __restrict__ Yb,
    const float* __restrict__ Xf, const float* __restrict__ Yf,
    const int* __restrict__ flag,
    const f16_t* __restrict__ Wh, const float* __restrict__ bconst,
    const float* __restrict__ ind,
    bf16_t* __restrict__ fusedB, float* __restrict__ fusedF,
    float* __restrict__ bsum, float* __restrict__ bmax)
{
  __shared__ __attribute__((aligned(16))) f16_t sbuf[4][130][40];
  __shared__ float sind[576], sconst[64];
  __shared__ float ssum[4][64], smax[4][64];
  const int rp = blockIdx.x, n = blockIdx.y;
  const int t = threadIdx.x, lane = t & 63, wv = t >> 6;
  const int l15 = lane & 15, quad = lane >> 4;
  const int ly = wv >> 1, ch2 = wv & 1;
  const int f32m = flag[0];
  const size_t nbase = (size_t)n * CH * HW;
  const f16_t* __restrict__ Whn = Wh + (size_t)n * 64 * 9 * 128;

  for (int i = t; i < 576; i += 256) sind[i] = ind[(size_t)n*576 + i];
  if (t < 64) sconst[t] = bconst[t];
  { // zero halo columns once (never re-written by staging)
    const int r = t >> 6, cs = (t >> 5) & 1, sl = t & 31;
    sbuf[r][cs ? 129 : 0][sl] = (f16_t)0.f;
  }

  f32x4 acc[4][4];
  #pragma unroll
  for (int i = 0; i < 4; ++i)
    #pragma unroll
    for (int j = 0; j < 4; ++j) acc[i][j] = (f32x4){0.f, 0.f, 0.f, 0.f};

  const int cstage = t & 127, rsel = t >> 7;

  for (int s = 0; s < 4; ++s) {
    __syncthreads();                      // prev reads done before restage
    #pragma unroll
    for (int pass = 0; pass < 2; ++pass) {
      const int r = rsel + 2*pass;
      const int gy = rp*2 - 1 + r;
      const bool valid = (gy >= 0) && (gy < H);
      const int colL = cstage + 1;
      #pragma unroll
      for (int oct = 0; oct < 4; ++oct) {
        f16x8 h;
        #pragma unroll
        for (int j = 0; j < 8; ++j) {
          const int g = s*32 + oct*8 + j;
          float v = 0.f;
          if (valid) {
            const size_t q = nbase + (size_t)(g & 63)*HW + gy*W + cstage;
            v = (g < 64) ? (f32m ? Xf[q] : (float)Xb[q])
                         : (f32m ? Yf[q] : (float)Yb[q]);
          }
          h[j] = (f16_t)v;
        }
        *(f16x8*)&sbuf[r][colL][(oct ^ (colL & 3)) * 8] = h;
      }
    }
    __syncthreads();

    #pragma unroll
    for (int tap = 0; tap < 9; ++tap) {
      const int ky = tap / 3, kx = tap % 3;
      f16x8 bfr[4];
      #pragma unroll
      for (int nt = 0; nt < 4; ++nt) {
        const int o = nt*16 + l15;
        bfr[nt] = *(const f16x8*)(Whn + ((o*9 + tap)*128 + s*32 + quad*8));
      }
      f16x8 afr[4];
      const int row = ly + ky;
      #pragma unroll
      for (int mt = 0; mt < 4; ++mt) {
        const int col = ch2*64 + mt*16 + l15 + kx;
        afr[mt] = *(const f16x8*)&sbuf[row][col][(quad ^ (col & 3)) * 8];
      }
      #pragma unroll
      for (int mt = 0; mt < 4; ++mt)
        #pragma unroll
        for (int nt = 0; nt < 4; ++nt)
          acc[mt][nt] = __builtin_amdgcn_mfma_f32_16x16x32_f16(afr[mt], bfr[nt], acc[mt][nt], 0, 0, 0);
    }
  }

  // ---- epilogue: + bconst + border const, ReLU, store, channel stats ----
  const int y = rp*2 + ly;
  const int yc = (y == 0) ? 0 : (y == H-1) ? 2 : 1;
  #pragma unroll
  for (int nt = 0; nt < 4; ++nt) {
    const int o = nt*16 + l15;
    const float bc = sconst[o];
    float ssm = 0.f, smx = 0.f;
    #pragma unroll
    for (int mt = 0; mt < 4; ++mt) {
      const int xb = ch2*64 + mt*16 + quad*4;
      f32x4 vals;
      #pragma unroll
      for (int r = 0; r < 4; ++r) {
        const int x = xb + r;
        const int xc = (x == 0) ? 0 : (x == W-1) ? 2 : 1;
        float v = acc[mt][nt][r] + bc + sind[(yc*3 + xc)*64 + o];
        v = fmaxf(v, 0.f);
        vals[r] = v; ssm += v; smx = fmaxf(smx, v);
      }
      const size_t off = nbase + (size_t)o*HW + y*W + xb;
      if (f32m) {
        *(f32x4*)(fusedF + off) = vals;
      } else {
        bf16x4 pv;
        #pragma unroll
        for (int r = 0; r < 4; ++r) pv[r] = (bf16_t)vals[r];
        *(bf16x4*)(fusedB + off) = pv;
      }
    }
    ssm += __shfl_xor(ssm, 16, 64); ssm += __shfl_xor(ssm, 32, 64);
    smx = fmaxf(smx, __shfl_xor(smx, 16, 64));
    smx = fmaxf(smx, __shfl_xor(smx, 32, 64));
    if (quad == 0) { ssum[wv][o] = ssm; smax[wv][o] = smx; }
  }
  __syncthreads();
  if (t < 64) {
    const float S = ssum[0][t] + ssum[1][t] + ssum[2][t] + ssum[3][t];
    const float M = fmaxf(fmaxf(smax[0][t], smax[1][t]), fmaxf(smax[2][t], smax[3][t]));
    bsum[((size_t)n*64 + rp)*64 + t] = S;
    bmax[((size_t)n*64 + rp)*64 + t] = M;
  }
}

// ===========================================================================
// K4: CBAM channel gate.  grid 16 (per n), block 64
// ===========================================================================
__global__ __launch_bounds__(64) void k4_chgate(
    const float* __restrict__ bsum, const float* __restrict__ bmax,
    const float* __restrict__ wt, float* __restrict__ chout)
{
  const int n = blockIdx.x, t = threadIdx.x;
  __shared__ float avg[64], mxs[64], h1[8], h2[8];
  float S = 0.f, M = 0.f;
  for (int rp = 0; rp < 64; ++rp) {
    S += bsum[((size_t)n*64 + rp)*64 + t];
    M = fmaxf(M, bmax[((size_t)n*64 + rp)*64 + t]);
  }
  avg[t] = S * (1.f / 16384.f);
  mxs[t] = M;
  __syncthreads();
  if (t < 8) {
    float s = wt[W_FC1B + t];
    for (int c = 0; c < 64; ++c) s += wt[W_FC1W + t*64 + c] * avg[c];
    h1[t] = fmaxf(s, 0.f);
  } else if (t < 16) {
    const int r = t - 8;
    float s = wt[W_FC1B + r];
    for (int c = 0; c < 64; ++c) s += wt[W_FC1W + r*64 + c] * mxs[c];
    h2[r] = fmaxf(s, 0.f);
  }
  __syncthreads();
  float s = 2.f * wt[W_FC2B + t];
  for (int r = 0; r < 8; ++r) s += wt[W_FC2W + t*8 + r] * (h1[r] + h2[r]);
  chout[n*64 + t] = 1.f / (1.f + expf(-s));
}

// ===========================================================================
// K5: spatial-attention inputs (per-pixel channel mean/max of fused*ch)
// ===========================================================================
__global__ __launch_bounds__(256) void k5_spin(
    const bf16_t* __restrict__ fusedB, const float* __restrict__ fusedF,
    const int* __restrict__ flag,
    const float* __restrict__ chs, float* __restrict__ spin)
{
  const int n = blockIdx.y;
  const int p = blockIdx.x * 256 + threadIdx.x;
  const int f32m = flag[0];
  const size_t nbase = (size_t)n * CH * HW;
  const float* c = chs + n * 64;
  float s = 0.f, m = 0.f;
  for (int o = 0; o < 64; ++o) {
    const float fv = f32m ? fusedF[nbase + (size_t)o*HW + p]
                          : (float)fusedB[nbase + (size_t)o*HW + p];
    const float v = fv * c[o];
    s += v; m = fmaxf(m, v);
  }
  spin[(size_t)n*2*HW + p]      = s * (1.f / 64.f);
  spin[(size_t)n*2*HW + HW + p] = m;
}

// ===========================================================================
// K6: 7x7 spatial conv + sigmoid + final scale (in-place on d_out, per flag)
// ===========================================================================
__global__ __launch_bounds__(256) void k6_final(
    bf16_t* __restrict__ fusedB, float* __restrict__ fusedF,
    const int* __restrict__ flag,
    const float* __restrict__ chs, const float* __restrict__ spin,
    const float* __restrict__ wt)
{
  const int n = blockIdx.y;
  const int p = blockIdx.x * 256 + threadIdx.x;
  const int y = p >> 7, x = p & 127;
  const int f32m = flag[0];
  const float* s0 = spin + (size_t)n*2*HW;
  const float* s1 = s0 + HW;
  float s = wt[W_SAB];
  for (int j = 0; j < 7; ++j) {
    const int yy = y + j - 3;
    if (yy < 0 || yy >= H) continue;
    for (int i = 0; i < 7; ++i) {
      const int xx = x + i - 3;
      if (xx < 0 || xx >= W) continue;
      const int q = yy * W + xx;
      s += wt[W_SAW + j*7 + i] * s0[q] + wt[W_SAW + 49 + j*7 + i] * s1[q];
    }
  }
  const float sp = 1.f / (1.f + expf(-s));
  const size_t nbase = (size_t)n * CH * HW;
  const float* c = chs + n * 64;
  for (int o = 0; o < 64; ++o) {
    const size_t q = nbase + (size_t)o*HW + p;
    if (f32m) fusedF[q] = fusedF[q] * c[o] * sp;
    else      fusedB[q] = (bf16_t)((float)fusedB[q] * c[o] * sp);
  }
}

// ===========================================================================
extern "C" void kernel_launch(void* const* d_in, const int* in_sizes, int n_in,
                              void* d_out, int out_size, void* d_ws, size_t ws_size,
                              hipStream_t stream)
{
  (void)n_in; (void)out_size; (void)ws_size; (void)in_sizes;
  char* ws = (char*)d_ws;
  float*  Gpart  = (float*)(ws + OFF_GPART);
  float*  sxp    = (float*)(ws + OFF_SX);
  float*  syp    = (float*)(ws + OFF_SY);
  float*  M1     = (float*)(ws + OFF_M1);
  float*  M2     = (float*)(ws + OFF_M2);
  float*  T1     = (float*)(ws + OFF_T1);
  float*  T2     = (float*)(ws + OFF_T2);
  float*  bconst = (float*)(ws + OFF_BCONST);
  f16_t*  Wh     = (f16_t*)(ws + OFF_WH);
  float*  windT  = (float*)(ws + OFF_WINDT);
  float*  indt   = (float*)(ws + OFF_IND);
  float*  bsum   = (float*)(ws + OFF_BSUM);
  float*  bmax   = (float*)(ws + OFF_BMAX);
  float*  chs    = (float*)(ws + OFF_CHS);
  float*  spin   = (float*)(ws + OFF_SPIN);
  int*    flag   = (int*)  (ws + OFF_FLAG);
  float*  wf32   = (float*)(ws + OFF_WF32);
  bf16_t* fusedB = (bf16_t*)d_out;
  float*  fusedF = (float*)d_out;

  const bf16_t* imgB = (const bf16_t*)d_in[0];
  const bf16_t* depB = (const bf16_t*)d_in[1];
  const float*  imgF = (const float*) d_in[0];
  const float*  depF = (const float*) d_in[1];

  WPack wp;
  static const int wsz[19] = {4096,64,4096,64,4096,64,1,73728,64,64,64,64,64,512,8,512,64,98,1};
  static const int woff[19] = {W_WQ,W_BQ,W_WK,W_BK,W_WV,W_BV,W_GAMMA,W_WF,W_BF,W_BNG,
                               W_BNB,W_BNM,W_BNV,W_FC1W,W_FC1B,W_FC2W,W_FC2B,W_SAW,W_SAB};
  for (int j = 0; j < 19; ++j) { wp.p[j] = d_in[2 + j]; wp.sz[j] = wsz[j]; wp.off[j] = woff[j]; }

  hipLaunchKernelGGL(k0_detect, dim3(1), dim3(256), 0, stream,
                     (const unsigned short*)d_in[0], flag);
  hipLaunchKernelGGL(kw_convert, dim3(288, 19), dim3(256), 0, stream, wp, flag, wf32);
  hipLaunchKernelGGL(k1_gram,  dim3(NCK, NI), dim3(256), 0, stream,
                     imgB, depB, imgF, depF, flag, Gpart, sxp, syp);
  hipLaunchKernelGGL(k2a_attn, dim3(NI), dim3(256), 0, stream,
                     Gpart, sxp, syp, wf32, M1, M2, T1, T2);
  hipLaunchKernelGGL(k2b_weff, dim3(9, 2, NI), dim3(256), 0, stream,
                     wf32, M1, M2, T1, T2, Wh, windT, bconst);
  hipLaunchKernelGGL(k2c_ind,  dim3(NI), dim3(64), 0, stream, windT, indt);
  hipLaunchKernelGGL(k3_conv,  dim3(64, NI), dim3(256), 0, stream,
                     imgB, depB, imgF, depF, flag, Wh, bconst, indt,
                     fusedB, fusedF, bsum, bmax);
  hipLaunchKernelGGL(k4_chgate, dim3(NI), dim3(64), 0, stream,
                     bsum, bmax, wf32, chs);
  hipLaunchKernelGGL(k5_spin,  dim3(64, NI), dim3(256), 0, stream,
                     fusedB, fusedF, flag, chs, spin);
  hipLaunchKernelGGL(k6_final, dim3(64, NI), dim3(256), 0, stream,
                     fusedB, fusedF, flag, chs, spin, wf32);
}